// Round 1
// baseline (2633.237 us; speedup 1.0000x reference)
//
#include <hip/hip_runtime.h>
#include <math.h>

// Problem constants (match reference)
#define B_  2
#define S_  2048
#define D_  1024
#define H_  16
#define DK_ 64

// ---------------------------------------------------------------------------
// Tiled fp32 GEMM: C[M,N] = A[M,K] @ W[K,N], row-major, M%128==0, N%128==0, K%8==0
// 256 threads, 128x128 tile, BK=8, 8x8 per thread (split 4+4 register tiles).
// ---------------------------------------------------------------------------
#define GM 128
#define GN 128
#define GK 8

__global__ __launch_bounds__(256) void gemm_f32(const float* __restrict__ A,
                                                const float* __restrict__ W,
                                                float* __restrict__ C,
                                                int M, int N, int K) {
    __shared__ float As[GK][GM];   // As[k][m] (transposed on store)
    __shared__ float Bs[GK][GN];   // Bs[k][n]

    const int tid  = threadIdx.x;
    const int bm   = blockIdx.y * GM;
    const int bn   = blockIdx.x * GN;
    const int trow = tid >> 4;          // 0..15
    const int tcol = tid & 15;          // 0..15

    // loaders
    const int lm  = tid >> 1;           // 0..127  (A row within tile)
    const int lk  = (tid & 1) * 4;      // 0 or 4  (A col-4 within BK)
    const int lbk = tid >> 5;           // 0..7    (B row within BK)
    const int lbn = (tid & 31) * 4;     // 0..124  (B col-4)

    float acc[8][8];
#pragma unroll
    for (int i = 0; i < 8; ++i)
#pragma unroll
        for (int j = 0; j < 8; ++j) acc[i][j] = 0.f;

    for (int k0 = 0; k0 < K; k0 += GK) {
        float4 av = *(const float4*)(A + (size_t)(bm + lm) * K + k0 + lk);
        float4 bv = *(const float4*)(W + (size_t)(k0 + lbk) * N + bn + lbn);
        __syncthreads();  // previous iter's compute done before overwrite
        As[lk + 0][lm] = av.x;
        As[lk + 1][lm] = av.y;
        As[lk + 2][lm] = av.z;
        As[lk + 3][lm] = av.w;
        *(float4*)&Bs[lbk][lbn] = bv;
        __syncthreads();
#pragma unroll
        for (int kk = 0; kk < GK; ++kk) {
            float4 a0 = *(const float4*)&As[kk][trow * 4];
            float4 a1 = *(const float4*)&As[kk][64 + trow * 4];
            float4 b0 = *(const float4*)&Bs[kk][tcol * 4];
            float4 b1 = *(const float4*)&Bs[kk][64 + tcol * 4];
            float a[8] = {a0.x, a0.y, a0.z, a0.w, a1.x, a1.y, a1.z, a1.w};
            float b[8] = {b0.x, b0.y, b0.z, b0.w, b1.x, b1.y, b1.z, b1.w};
#pragma unroll
            for (int i = 0; i < 8; ++i)
#pragma unroll
                for (int j = 0; j < 8; ++j) acc[i][j] += a[i] * b[j];
        }
    }

#pragma unroll
    for (int i = 0; i < 8; ++i) {
        int m = bm + ((i < 4) ? (trow * 4 + i) : (64 + trow * 4 + (i - 4)));
        float4 c0 = {acc[i][0], acc[i][1], acc[i][2], acc[i][3]};
        float4 c1 = {acc[i][4], acc[i][5], acc[i][6], acc[i][7]};
        *(float4*)(C + (size_t)m * N + bn + tcol * 4) = c0;
        *(float4*)(C + (size_t)m * N + bn + 64 + tcol * 4) = c1;
    }
}

// ---------------------------------------------------------------------------
// Flash-style attention, fp32. One block = one (b, h, 32-query tile).
// Q/K/V layout: [b*S + s][h*64 + d]  (i.e. the raw GEMM outputs).
// bias layout: [1, H, S, S].
// ctx output:  [b*S + s][h*64 + d].
// ---------------------------------------------------------------------------
#define TQ 32
#define TK 32

__global__ __launch_bounds__(256) void attn_flash(const float* __restrict__ Qp,
                                                  const float* __restrict__ Kp,
                                                  const float* __restrict__ Vp,
                                                  const float* __restrict__ bias,
                                                  float* __restrict__ ctx) {
    __shared__ float Qs[TQ][64];
    __shared__ float Ks[TK][66];   // pad 66: float2 reads are 2-way (free)
    __shared__ float Vs[TK][64];
    __shared__ float Ps[TQ][TK];
    __shared__ float ms[TQ];
    __shared__ float ls[TQ];
    __shared__ float alphas[TQ];

    const int tid = threadIdx.x;
    int gid = blockIdx.x;
    const int qt = gid & 63;          // S/TQ = 64 query tiles
    const int h  = (gid >> 6) & 15;
    const int b  = gid >> 10;

    const int q0 = qt * TQ;

    // --- load Q tile, init m/l ---
    const float* Qbase = Qp + ((size_t)(b * S_ + q0)) * D_ + h * DK_;
#pragma unroll
    for (int i = 0; i < 2; ++i) {
        int t = tid + i * 256;
        int row = t >> 4;
        int col = (t & 15) * 4;
        *(float4*)&Qs[row][col] = *(const float4*)(Qbase + (size_t)row * D_ + col);
    }
    if (tid < TQ) {
        ms[tid] = -INFINITY;
        ls[tid] = 0.f;
    }

    // PV-phase thread mapping
    const int d   = tid & 63;
    const int qg2 = tid >> 6;   // 0..3 ; rows qg2*8 .. qg2*8+7
    float acc[8];
#pragma unroll
    for (int i = 0; i < 8; ++i) acc[i] = 0.f;

    // score-phase thread mapping
    const int jl = tid & 31;
    const int qg = tid >> 5;    // 0..7 ; rows qg, qg+8, qg+16, qg+24

    __syncthreads();

    for (int kt = 0; kt < S_ / TK; ++kt) {
        const int j0 = kt * TK;
        const float* Kbase = Kp + ((size_t)(b * S_ + j0)) * D_ + h * DK_;
        const float* Vbase = Vp + ((size_t)(b * S_ + j0)) * D_ + h * DK_;
#pragma unroll
        for (int i = 0; i < 2; ++i) {
            int t = tid + i * 256;
            int row = t >> 4;
            int col = (t & 15) * 4;
            float4 kv = *(const float4*)(Kbase + (size_t)row * D_ + col);
            Ks[row][col + 0] = kv.x;
            Ks[row][col + 1] = kv.y;
            Ks[row][col + 2] = kv.z;
            Ks[row][col + 3] = kv.w;
            *(float4*)&Vs[row][col] = *(const float4*)(Vbase + (size_t)row * D_ + col);
        }
        __syncthreads();

        // --- scores + online softmax state update ---
        const float2* kr = (const float2*)&Ks[jl][0];
#pragma unroll
        for (int qi = 0; qi < 4; ++qi) {
            const int q = qg + qi * 8;
            const float2* qr = (const float2*)&Qs[q][0];
            float s = 0.f;
#pragma unroll
            for (int t = 0; t < 32; ++t)
                s += qr[t].x * kr[t].x + qr[t].y * kr[t].y;
            s += bias[((size_t)h * S_ + (q0 + q)) * S_ + j0 + jl];

            // row max across the 32 lanes of this half-wave
            float rm = s;
            rm = fmaxf(rm, __shfl_xor(rm, 16));
            rm = fmaxf(rm, __shfl_xor(rm, 8));
            rm = fmaxf(rm, __shfl_xor(rm, 4));
            rm = fmaxf(rm, __shfl_xor(rm, 2));
            rm = fmaxf(rm, __shfl_xor(rm, 1));

            float mo   = ms[q];
            float mn   = fmaxf(mo, rm);
            float alph = __expf(mo - mn);   // 0 when mo == -inf
            float e    = __expf(s - mn);
            Ps[q][jl]  = e;

            float rs = e;
            rs += __shfl_xor(rs, 16);
            rs += __shfl_xor(rs, 8);
            rs += __shfl_xor(rs, 4);
            rs += __shfl_xor(rs, 2);
            rs += __shfl_xor(rs, 1);

            if (jl == 0) {
                ms[q]     = mn;
                ls[q]     = ls[q] * alph + rs;
                alphas[q] = alph;
            }
        }
        __syncthreads();

        // --- PV accumulate ---
#pragma unroll
        for (int qi = 0; qi < 8; ++qi) acc[qi] *= alphas[qg2 * 8 + qi];
        for (int j = 0; j < TK; ++j) {
            float v = Vs[j][d];
#pragma unroll
            for (int qi = 0; qi < 8; ++qi) acc[qi] += Ps[qg2 * 8 + qi][j] * v;
        }
        __syncthreads();  // PV done before next tile overwrites Ks/Vs/Ps
    }

    // --- write ctx ---
#pragma unroll
    for (int qi = 0; qi < 8; ++qi) {
        int q = qg2 * 8 + qi;
        float val = acc[qi] / ls[q];
        ctx[((size_t)(b * S_ + q0 + q)) * D_ + h * DK_ + d] = val;
    }
}

// ---------------------------------------------------------------------------
// Launch
// ---------------------------------------------------------------------------
extern "C" void kernel_launch(void* const* d_in, const int* in_sizes, int n_in,
                              void* d_out, int out_size, void* d_ws, size_t ws_size,
                              hipStream_t stream) {
    const float* hs   = (const float*)d_in[0];  // [B,S,D]
    const float* bias = (const float*)d_in[1];  // [1,H,S,S]
    // d_in[2] = key_value_states (unused: self-attention branch)
    const float* wq   = (const float*)d_in[3];
    const float* wk   = (const float*)d_in[4];
    const float* wv   = (const float*)d_in[5];
    const float* wo   = (const float*)d_in[6];
    float* out = (float*)d_out;

    const size_t elems = (size_t)B_ * S_ * D_;  // 4,194,304
    float* qb = (float*)d_ws;
    float* kb = qb + elems;
    float* vb = kb + elems;
    float* cb = vb + elems;

    const int M = B_ * S_;  // 4096
    dim3 gg(D_ / GN, M / GM);  // (8, 32)
    gemm_f32<<<gg, 256, 0, stream>>>(hs, wq, qb, M, D_, D_);
    gemm_f32<<<gg, 256, 0, stream>>>(hs, wk, kb, M, D_, D_);
    gemm_f32<<<gg, 256, 0, stream>>>(hs, wv, vb, M, D_, D_);

    attn_flash<<<B_ * H_ * (S_ / TQ), 256, 0, stream>>>(qb, kb, vb, bias, cb);

    gemm_f32<<<gg, 256, 0, stream>>>(cb, wo, out, M, D_, D_);
}

// Round 2
// 684.098 us; speedup vs baseline: 3.8492x; 3.8492x over previous
//
#include <hip/hip_runtime.h>
#include <math.h>

#define B_  2
#define S_  2048
#define D_  1024
#define H_  16
#define DK_ 64

typedef float f32x4 __attribute__((ext_vector_type(4)));
typedef short short8 __attribute__((ext_vector_type(8)));
typedef unsigned short u16;

static __device__ __forceinline__ u16 f2bf(float x) {
    union { float f; unsigned u; } v; v.f = x;
    unsigned r = v.u + 0x7fffu + ((v.u >> 16) & 1u);
    return (u16)(r >> 16);
}

static __device__ __forceinline__ void gload_lds16(const void* g, void* l) {
    __builtin_amdgcn_global_load_lds((const __attribute__((address_space(1))) void*)g,
                                     (__attribute__((address_space(3))) void*)l,
                                     16, 0, 0);
}

#define MFMA16(a, b, c) __builtin_amdgcn_mfma_f32_16x16x32_bf16((a), (b), (c), 0, 0, 0)

// ---------------------------------------------------------------------------
// fp32 -> bf16 elementwise cast (8 elems/thread, exact-cover launch)
// ---------------------------------------------------------------------------
__global__ __launch_bounds__(256) void cast_bf16(const float* __restrict__ X,
                                                 u16* __restrict__ Y) {
    int i = (blockIdx.x * 256 + threadIdx.x) * 8;
    float4 a = *(const float4*)(X + i);
    float4 b = *(const float4*)(X + i + 4);
    short8 o;
    o[0] = (short)f2bf(a.x); o[1] = (short)f2bf(a.y);
    o[2] = (short)f2bf(a.z); o[3] = (short)f2bf(a.w);
    o[4] = (short)f2bf(b.x); o[5] = (short)f2bf(b.y);
    o[6] = (short)f2bf(b.z); o[7] = (short)f2bf(b.w);
    *(short8*)(Y + i) = o;
}

// ---------------------------------------------------------------------------
// W[k][n] fp32 -> Wt[n][k] bf16  (32x32 LDS tile transpose)
// ---------------------------------------------------------------------------
__global__ __launch_bounds__(256) void transpose_cast(const float* __restrict__ W,
                                                      u16* __restrict__ Wt,
                                                      int K, int N) {
    __shared__ float t[32][33];
    int tx = threadIdx.x & 31, ty = threadIdx.x >> 5;
    int n0 = blockIdx.x * 32, k0 = blockIdx.y * 32;
#pragma unroll
    for (int r = ty; r < 32; r += 8)
        t[r][tx] = W[(size_t)(k0 + r) * N + n0 + tx];
    __syncthreads();
#pragma unroll
    for (int r = ty; r < 32; r += 8)
        Wt[(size_t)(n0 + r) * K + k0 + tx] = f2bf(t[tx][r]);
}

// ---------------------------------------------------------------------------
// bf16 MFMA GEMM, m97 structure: 128x128 tile, BK=32, global_load_lds(16B),
// A [M][K] bf16, Bt [N][K] bf16 (pre-transposed weights).
// MODE 0: fused QKV epilogue -> Qb [M][1024], Kb [M][1024], Vt [b][h][d][s]
// MODE 2: fp32 out [M][N]
// ---------------------------------------------------------------------------
template <int MODE>
__global__ __launch_bounds__(256) void gemm_bf16(const u16* __restrict__ A,
                                                 const u16* __restrict__ Bt,
                                                 void* __restrict__ C0,
                                                 u16* __restrict__ Kb,
                                                 u16* __restrict__ Vt,
                                                 int M, int N, int K) {
    __shared__ alignas(16) u16 As[128 * 32];
    __shared__ alignas(16) u16 Bs[128 * 32];

    const int tid  = threadIdx.x;
    const int wave = tid >> 6;
    const int lane = tid & 63;
    const int col  = lane & 15;
    const int quad = lane >> 4;
    const int bm   = blockIdx.y * 128;
    const int bn   = blockIdx.x * 128;
    const int wm   = (wave >> 1) * 64;
    const int wn   = (wave & 1) * 64;

    f32x4 acc[4][4];
#pragma unroll
    for (int i = 0; i < 4; ++i)
#pragma unroll
        for (int j = 0; j < 4; ++j) acc[i][j] = (f32x4){0.f, 0.f, 0.f, 0.f};

    // staging: wave w owns 1KB chunks 2w, 2w+1 of each 8KB tile
    const int srow = wave * 32 + (lane >> 2);  // + 0 / +16 for the two chunks
    const int ksel = (lane & 3) * 8;           // element offset (16B units)
    const u16* ga0 = A  + (size_t)(bm + srow) * K + ksel;
    const u16* ga1 = ga0 + (size_t)16 * K;
    const u16* gb0 = Bt + (size_t)(bn + srow) * K + ksel;
    const u16* gb1 = gb0 + (size_t)16 * K;
    char* la0 = (char*)As + wave * 2048;
    char* la1 = la0 + 1024;
    char* lb0 = (char*)Bs + wave * 2048;
    char* lb1 = lb0 + 1024;

    for (int k0 = 0; k0 < K; k0 += 32) {
        __syncthreads();
        gload_lds16(ga0 + k0, la0);
        gload_lds16(ga1 + k0, la1);
        gload_lds16(gb0 + k0, lb0);
        gload_lds16(gb1 + k0, lb1);
        __syncthreads();
        short8 af[4], bfr[4];
#pragma unroll
        for (int mi = 0; mi < 4; ++mi)
            af[mi] = *(const short8*)&As[(wm + mi * 16 + col) * 32 + quad * 8];
#pragma unroll
        for (int ni = 0; ni < 4; ++ni)
            bfr[ni] = *(const short8*)&Bs[(wn + ni * 16 + col) * 32 + quad * 8];
#pragma unroll
        for (int mi = 0; mi < 4; ++mi)
#pragma unroll
            for (int ni = 0; ni < 4; ++ni)
                acc[mi][ni] = MFMA16(af[mi], bfr[ni], acc[mi][ni]);
    }

#pragma unroll
    for (int mi = 0; mi < 4; ++mi)
#pragma unroll
        for (int ni = 0; ni < 4; ++ni) {
            const int rowb = bm + wm + mi * 16 + quad * 4;
            const int coln = bn + wn + ni * 16 + col;
            f32x4 v = acc[mi][ni];
            if (MODE == 2) {
                float* O = (float*)C0;
#pragma unroll
                for (int r = 0; r < 4; ++r)
                    O[(size_t)(rowb + r) * N + coln] = v[r];
            } else {
                if (coln < D_) {
                    u16* Qb = (u16*)C0;
#pragma unroll
                    for (int r = 0; r < 4; ++r)
                        Qb[(size_t)(rowb + r) * D_ + coln] = f2bf(v[r]);
                } else if (coln < 2 * D_) {
#pragma unroll
                    for (int r = 0; r < 4; ++r)
                        Kb[(size_t)(rowb + r) * D_ + (coln - D_)] = f2bf(v[r]);
                } else {
                    const int nn = coln - 2 * D_;
                    const int hh = nn >> 6, d = nn & 63;
                    const int bb = rowb >> 11, sb = rowb & 2047;
                    ushort4 pk;
                    pk.x = f2bf(v[0]); pk.y = f2bf(v[1]);
                    pk.z = f2bf(v[2]); pk.w = f2bf(v[3]);
                    *(ushort4*)&Vt[(((size_t)bb * H_ + hh) * DK_ + d) * S_ + sb] = pk;
                }
            }
        }
}

// ---------------------------------------------------------------------------
// MFMA flash attention: block = (b, h, 64-query tile); wave = 16 queries.
// No __syncthreads — waves independent. Q/K/Vt frags read direct from global.
// P transform C->A layout via per-wave LDS (fp32, row stride 68).
// ---------------------------------------------------------------------------
__global__ __launch_bounds__(256) void attn_mfma(const u16* __restrict__ Qb,
                                                 const u16* __restrict__ Kb,
                                                 const u16* __restrict__ Vt,
                                                 const float* __restrict__ bias,
                                                 u16* __restrict__ Ctx) {
    __shared__ alignas(16) float Ps[4][16][68];

    const int tid  = threadIdx.x;
    const int wave = tid >> 6;
    const int lane = tid & 63;
    const int col  = lane & 15;
    const int quad = lane >> 4;

    const int gid = blockIdx.x;
    const int qt  = gid & 31;
    const int h   = (gid >> 5) & 15;
    const int b   = gid >> 9;
    const int q0  = qt * 64 + wave * 16;

    // Q A-fragments (k = kg*32 + quad*8 + j)
    short8 aq[2];
    {
        const u16* qp = Qb + (size_t)(b * S_ + q0 + col) * D_ + h * 64 + quad * 8;
        aq[0] = *(const short8*)qp;
        aq[1] = *(const short8*)(qp + 32);
    }

    f32x4 o[4];
#pragma unroll
    for (int i = 0; i < 4; ++i) o[i] = (f32x4){0.f, 0.f, 0.f, 0.f};
    float mst[4], lst[4];
#pragma unroll
    for (int r = 0; r < 4; ++r) { mst[r] = -INFINITY; lst[r] = 0.f; }

    const float* bias_base = bias + ((size_t)h * S_ + (q0 + quad * 4)) * S_;
    const u16*   kb_base   = Kb + (size_t)(b * S_) * D_ + h * 64 + quad * 8;
    const u16*   vt_base   = Vt + ((size_t)b * H_ + h) * DK_ * S_ + quad * 8;

    for (int j0 = 0; j0 < S_; j0 += 64) {
        // ---- S = Q K^T (16 x 64 scores per wave) ----
        f32x4 sc[4];
#pragma unroll
        for (int ng = 0; ng < 4; ++ng) {
            const u16* kp = kb_base + (size_t)(j0 + ng * 16 + col) * D_;
            short8 bk0 = *(const short8*)kp;
            short8 bk1 = *(const short8*)(kp + 32);
            f32x4 z = (f32x4){0.f, 0.f, 0.f, 0.f};
            z = MFMA16(aq[0], bk0, z);
            z = MFMA16(aq[1], bk1, z);
            sc[ng] = z;
        }
        // ---- + bias ----
#pragma unroll
        for (int ng = 0; ng < 4; ++ng)
#pragma unroll
            for (int r = 0; r < 4; ++r)
                sc[ng][r] += bias_base[(size_t)r * S_ + j0 + ng * 16 + col];

        // ---- online softmax (rows = quad*4+r, cols across 16 lanes) ----
        float alpha[4], rs[4];
#pragma unroll
        for (int r = 0; r < 4; ++r) {
            float rm = fmaxf(fmaxf(sc[0][r], sc[1][r]), fmaxf(sc[2][r], sc[3][r]));
            rm = fmaxf(rm, __shfl_xor(rm, 1));
            rm = fmaxf(rm, __shfl_xor(rm, 2));
            rm = fmaxf(rm, __shfl_xor(rm, 4));
            rm = fmaxf(rm, __shfl_xor(rm, 8));
            float mn = fmaxf(mst[r], rm);
            alpha[r] = __expf(mst[r] - mn);
            mst[r] = mn;
            rs[r] = 0.f;
        }
#pragma unroll
        for (int ng = 0; ng < 4; ++ng)
#pragma unroll
            for (int r = 0; r < 4; ++r) {
                float p = __expf(sc[ng][r] - mst[r]);
                sc[ng][r] = p;
                rs[r] += p;
            }
#pragma unroll
        for (int r = 0; r < 4; ++r) {
            float s = rs[r];
            s += __shfl_xor(s, 1);
            s += __shfl_xor(s, 2);
            s += __shfl_xor(s, 4);
            s += __shfl_xor(s, 8);
            lst[r] = lst[r] * alpha[r] + s;
        }
        // ---- rescale O ----
#pragma unroll
        for (int ndg = 0; ndg < 4; ++ndg)
#pragma unroll
            for (int r = 0; r < 4; ++r) o[ndg][r] *= alpha[r];

        // ---- P: C-layout -> A-layout via LDS ----
#pragma unroll
        for (int ng = 0; ng < 4; ++ng)
#pragma unroll
            for (int r = 0; r < 4; ++r)
                Ps[wave][quad * 4 + r][ng * 16 + col] = sc[ng][r];

        short8 ap[2];
#pragma unroll
        for (int kg = 0; kg < 2; ++kg) {
            f32x4 p0 = *(const f32x4*)&Ps[wave][col][kg * 32 + quad * 8];
            f32x4 p1 = *(const f32x4*)&Ps[wave][col][kg * 32 + quad * 8 + 4];
            short8 t;
            t[0] = (short)f2bf(p0[0]); t[1] = (short)f2bf(p0[1]);
            t[2] = (short)f2bf(p0[2]); t[3] = (short)f2bf(p0[3]);
            t[4] = (short)f2bf(p1[0]); t[5] = (short)f2bf(p1[1]);
            t[6] = (short)f2bf(p1[2]); t[7] = (short)f2bf(p1[3]);
            ap[kg] = t;
        }

        // ---- O += P V ----
#pragma unroll
        for (int ndg = 0; ndg < 4; ++ndg) {
            const u16* vp = vt_base + (size_t)(ndg * 16 + col) * S_ + j0;
            short8 bv0 = *(const short8*)vp;
            short8 bv1 = *(const short8*)(vp + 32);
            o[ndg] = MFMA16(ap[0], bv0, o[ndg]);
            o[ndg] = MFMA16(ap[1], bv1, o[ndg]);
        }
    }

    // ---- epilogue: normalize, write ctx bf16 [b*S+s][h*64+d] ----
    float inv[4];
#pragma unroll
    for (int r = 0; r < 4; ++r) inv[r] = 1.f / lst[r];
#pragma unroll
    for (int ndg = 0; ndg < 4; ++ndg)
#pragma unroll
        for (int r = 0; r < 4; ++r)
            Ctx[(size_t)(b * S_ + q0 + quad * 4 + r) * D_ + h * 64 + ndg * 16 + col] =
                f2bf(o[ndg][r] * inv[r]);
}

// ---------------------------------------------------------------------------
// Launch
// ---------------------------------------------------------------------------
extern "C" void kernel_launch(void* const* d_in, const int* in_sizes, int n_in,
                              void* d_out, int out_size, void* d_ws, size_t ws_size,
                              hipStream_t stream) {
    const float* hs   = (const float*)d_in[0];  // [B,S,D]
    const float* bias = (const float*)d_in[1];  // [1,H,S,S]
    const float* wq   = (const float*)d_in[3];
    const float* wk   = (const float*)d_in[4];
    const float* wv   = (const float*)d_in[5];
    const float* wo   = (const float*)d_in[6];
    float* out = (float*)d_out;

    const size_t elems = (size_t)B_ * S_ * D_;  // 4,194,304
    char* ws = (char*)d_ws;
    u16* hs_bf = (u16*)ws;                       // 8 MB
    u16* qb    = (u16*)(ws + 8 * 1024 * 1024);   // 8 MB
    u16* kb    = (u16*)(ws + 16 * 1024 * 1024);  // 8 MB
    u16* vt    = (u16*)(ws + 24 * 1024 * 1024);  // 8 MB
    u16* cb    = (u16*)(ws + 32 * 1024 * 1024);  // 8 MB
    u16* wqt   = (u16*)(ws + 40 * 1024 * 1024);  // 2 MB  (wqt/wkt/wvt contiguous!)
    u16* wkt   = (u16*)(ws + 42 * 1024 * 1024);  // 2 MB
    u16* wvt   = (u16*)(ws + 44 * 1024 * 1024);  // 2 MB
    u16* wot   = (u16*)(ws + 46 * 1024 * 1024);  // 2 MB

    const int M = B_ * S_;  // 4096

    cast_bf16<<<(int)(elems / (256 * 8)), 256, 0, stream>>>(hs, hs_bf);
    dim3 tg(D_ / 32, D_ / 32);
    transpose_cast<<<tg, 256, 0, stream>>>(wq, wqt, D_, D_);
    transpose_cast<<<tg, 256, 0, stream>>>(wk, wkt, D_, D_);
    transpose_cast<<<tg, 256, 0, stream>>>(wv, wvt, D_, D_);
    transpose_cast<<<tg, 256, 0, stream>>>(wo, wot, D_, D_);

    // fused QKV: Bt = [wqt; wkt; wvt] as a 3072x1024 matrix
    gemm_bf16<0><<<dim3(3 * D_ / 128, M / 128), 256, 0, stream>>>(
        hs_bf, wqt, (void*)qb, kb, vt, M, 3 * D_, D_);

    attn_mfma<<<B_ * H_ * (S_ / 64), 256, 0, stream>>>(qb, kb, vt, bias, cb);

    gemm_bf16<2><<<dim3(D_ / 128, M / 128), 256, 0, stream>>>(
        cb, wot, (void*)out, nullptr, nullptr, M, D_, D_);
}

// Round 3
// 528.631 us; speedup vs baseline: 4.9812x; 1.2941x over previous
//
#include <hip/hip_runtime.h>
#include <math.h>

#define B_  2
#define S_  2048
#define D_  1024
#define H_  16
#define DK_ 64

typedef float f32x4 __attribute__((ext_vector_type(4)));
typedef short short8 __attribute__((ext_vector_type(8)));
typedef unsigned short u16;

static __device__ __forceinline__ u16 f2bf(float x) {
    union { float f; unsigned u; } v; v.f = x;
    unsigned r = v.u + 0x7fffu + ((v.u >> 16) & 1u);
    return (u16)(r >> 16);
}

static __device__ __forceinline__ void gload_lds16(const void* g, void* l) {
    __builtin_amdgcn_global_load_lds((const __attribute__((address_space(1))) void*)g,
                                     (__attribute__((address_space(3))) void*)l,
                                     16, 0, 0);
}

#define MFMA16(a, b, c) __builtin_amdgcn_mfma_f32_16x16x32_bf16((a), (b), (c), 0, 0, 0)

// ---------------------------------------------------------------------------
// fp32 -> bf16 elementwise cast
// ---------------------------------------------------------------------------
__global__ __launch_bounds__(256) void cast_bf16(const float* __restrict__ X,
                                                 u16* __restrict__ Y) {
    int i = (blockIdx.x * 256 + threadIdx.x) * 8;
    float4 a = *(const float4*)(X + i);
    float4 b = *(const float4*)(X + i + 4);
    short8 o;
    o[0] = (short)f2bf(a.x); o[1] = (short)f2bf(a.y);
    o[2] = (short)f2bf(a.z); o[3] = (short)f2bf(a.w);
    o[4] = (short)f2bf(b.x); o[5] = (short)f2bf(b.y);
    o[6] = (short)f2bf(b.z); o[7] = (short)f2bf(b.w);
    *(short8*)(Y + i) = o;
}

// ---------------------------------------------------------------------------
// Four 1024x1024 W[k][n] fp32 -> Wt[n][k] bf16 transposes in one launch
// ---------------------------------------------------------------------------
__global__ __launch_bounds__(256) void transpose_cast4(const float* __restrict__ w0,
                                                       const float* __restrict__ w1,
                                                       const float* __restrict__ w2,
                                                       const float* __restrict__ w3,
                                                       u16* __restrict__ o0,
                                                       u16* __restrict__ o1,
                                                       u16* __restrict__ o2,
                                                       u16* __restrict__ o3) {
    __shared__ float t[32][33];
    const float* W; u16* O;
    switch (blockIdx.z) {
        case 0: W = w0; O = o0; break;
        case 1: W = w1; O = o1; break;
        case 2: W = w2; O = o2; break;
        default: W = w3; O = o3; break;
    }
    const int K = 1024, N = 1024;
    int tx = threadIdx.x & 31, ty = threadIdx.x >> 5;
    int n0 = blockIdx.x * 32, k0 = blockIdx.y * 32;
#pragma unroll
    for (int r = ty; r < 32; r += 8)
        t[r][tx] = W[(size_t)(k0 + r) * N + n0 + tx];
    __syncthreads();
#pragma unroll
    for (int r = ty; r < 32; r += 8)
        O[(size_t)(n0 + r) * K + k0 + tx] = f2bf(t[tx][r]);
}

// ---------------------------------------------------------------------------
// bf16 MFMA GEMM (m97 structure) — unchanged from validated round 2.
// MODE 0: fused QKV epilogue -> Qb, Kb, Vt[b][h][d][s].  MODE 2: fp32 out.
// ---------------------------------------------------------------------------
template <int MODE>
__global__ __launch_bounds__(256) void gemm_bf16(const u16* __restrict__ A,
                                                 const u16* __restrict__ Bt,
                                                 void* __restrict__ C0,
                                                 u16* __restrict__ Kb,
                                                 u16* __restrict__ Vt,
                                                 int M, int N, int K) {
    __shared__ alignas(16) u16 As[128 * 32];
    __shared__ alignas(16) u16 Bs[128 * 32];

    const int tid  = threadIdx.x;
    const int wave = tid >> 6;
    const int lane = tid & 63;
    const int col  = lane & 15;
    const int quad = lane >> 4;
    const int bm   = blockIdx.y * 128;
    const int bn   = blockIdx.x * 128;
    const int wm   = (wave >> 1) * 64;
    const int wn   = (wave & 1) * 64;

    f32x4 acc[4][4];
#pragma unroll
    for (int i = 0; i < 4; ++i)
#pragma unroll
        for (int j = 0; j < 4; ++j) acc[i][j] = (f32x4){0.f, 0.f, 0.f, 0.f};

    const int srow = wave * 32 + (lane >> 2);
    const int ksel = (lane & 3) * 8;
    const u16* ga0 = A  + (size_t)(bm + srow) * K + ksel;
    const u16* ga1 = ga0 + (size_t)16 * K;
    const u16* gb0 = Bt + (size_t)(bn + srow) * K + ksel;
    const u16* gb1 = gb0 + (size_t)16 * K;
    char* la0 = (char*)As + wave * 2048;
    char* la1 = la0 + 1024;
    char* lb0 = (char*)Bs + wave * 2048;
    char* lb1 = lb0 + 1024;

    for (int k0 = 0; k0 < K; k0 += 32) {
        __syncthreads();
        gload_lds16(ga0 + k0, la0);
        gload_lds16(ga1 + k0, la1);
        gload_lds16(gb0 + k0, lb0);
        gload_lds16(gb1 + k0, lb1);
        __syncthreads();
        short8 af[4], bfr[4];
#pragma unroll
        for (int mi = 0; mi < 4; ++mi)
            af[mi] = *(const short8*)&As[(wm + mi * 16 + col) * 32 + quad * 8];
#pragma unroll
        for (int ni = 0; ni < 4; ++ni)
            bfr[ni] = *(const short8*)&Bs[(wn + ni * 16 + col) * 32 + quad * 8];
#pragma unroll
        for (int mi = 0; mi < 4; ++mi)
#pragma unroll
            for (int ni = 0; ni < 4; ++ni)
                acc[mi][ni] = MFMA16(af[mi], bfr[ni], acc[mi][ni]);
    }

#pragma unroll
    for (int mi = 0; mi < 4; ++mi)
#pragma unroll
        for (int ni = 0; ni < 4; ++ni) {
            const int rowb = bm + wm + mi * 16 + quad * 4;
            const int coln = bn + wn + ni * 16 + col;
            f32x4 v = acc[mi][ni];
            if (MODE == 2) {
                float* O = (float*)C0;
#pragma unroll
                for (int r = 0; r < 4; ++r)
                    O[(size_t)(rowb + r) * N + coln] = v[r];
            } else {
                if (coln < D_) {
                    u16* Qb = (u16*)C0;
#pragma unroll
                    for (int r = 0; r < 4; ++r)
                        Qb[(size_t)(rowb + r) * D_ + coln] = f2bf(v[r]);
                } else if (coln < 2 * D_) {
#pragma unroll
                    for (int r = 0; r < 4; ++r)
                        Kb[(size_t)(rowb + r) * D_ + (coln - D_)] = f2bf(v[r]);
                } else {
                    const int nn = coln - 2 * D_;
                    const int hh = nn >> 6, d = nn & 63;
                    const int bb = rowb >> 11, sb = rowb & 2047;
                    ushort4 pk;
                    pk.x = f2bf(v[0]); pk.y = f2bf(v[1]);
                    pk.z = f2bf(v[2]); pk.w = f2bf(v[3]);
                    *(ushort4*)&Vt[(((size_t)bb * H_ + hh) * DK_ + d) * S_ + sb] = pk;
                }
            }
        }
}

// ---------------------------------------------------------------------------
// MFMA flash attention v2: block = (b,h,64-query tile), 4 waves x 16 queries.
// K/V tiles (64 keys) cooperatively staged to LDS, double-buffered, XOR-swizzled
// (gload_lds requires lane-contiguous dest; swizzle makes b128 frag reads
// conflict-free). P buffer bf16 swizzled, 2KB/wave. LDS total = 40960 = 4 blk/CU.
// One __syncthreads per iter; stage(it+1) issued after it so the barrier's
// vmcnt(0) drain only waits loads issued a full compute-phase earlier.
// ---------------------------------------------------------------------------
__global__ __launch_bounds__(256, 4) void attn_mfma(const u16* __restrict__ Qb,
                                                    const u16* __restrict__ Kb,
                                                    const u16* __restrict__ Vt,
                                                    const float* __restrict__ bias,
                                                    u16* __restrict__ Ctx) {
    __shared__ alignas(16) char smem[40960];  // K0 V0 K1 V1 (8KB each) + Ps 8KB

    const int tid  = threadIdx.x;
    const int wave = tid >> 6;
    const int lane = tid & 63;
    const int col  = lane & 15;
    const int quad = lane >> 4;
    const int cx   = col & 7;           // XOR swizzle key for frag reads
    const int sl0  = (quad ^ cx) * 16;  // chunk kg=0 slot byte offset
    const int sl1  = ((4 + quad) ^ cx) * 16;

    const int gid = blockIdx.x;
    const int qt  = gid & 31;
    const int h   = (gid >> 5) & 15;
    const int b   = gid >> 9;
    const int q0  = qt * 64 + wave * 16;

    // Q A-fragments (row = col, k = kg*32 + quad*8 + j)
    short8 aq0, aq1;
    {
        const u16* qp = Qb + (size_t)(b * S_ + q0 + col) * D_ + h * 64 + quad * 8;
        aq0 = *(const short8*)qp;
        aq1 = *(const short8*)(qp + 32);
    }

    // staging thread-constants: chunk c covers (row = c>>3, slot = c&7),
    // slot s of row holds global 16B-chunk g = s ^ (row&7).
    const int c0 = tid, c1 = tid + 256;
    const int r0 = c0 >> 3, g0 = (c0 & 7) ^ (r0 & 7);
    const int r1 = c1 >> 3, g1 = (c1 & 7) ^ (r1 & 7);
    const u16* kT = Kb + (size_t)b * S_ * D_ + h * 64;          // + (j0+row)*D + g*8
    const u16* vT = Vt + ((size_t)b * H_ + h) * (size_t)64 * S_; // + row*S + j0 + g*8
    const size_t kOff0 = (size_t)r0 * D_ + g0 * 8;
    const size_t kOff1 = (size_t)r1 * D_ + g1 * 8;
    const size_t vOff0 = (size_t)r0 * S_ + g0 * 8;
    const size_t vOff1 = (size_t)r1 * S_ + g1 * 8;

    auto stage = [&](int j0s, int bis) {
        char* base = smem + bis * 16384;
        gload_lds16(kT + (size_t)j0s * D_ + kOff0, base + wave * 1024);
        gload_lds16(kT + (size_t)j0s * D_ + kOff1, base + 4096 + wave * 1024);
        gload_lds16(vT + j0s + vOff0, base + 8192 + wave * 1024);
        gload_lds16(vT + j0s + vOff1, base + 12288 + wave * 1024);
    };

    f32x4 o[4];
#pragma unroll
    for (int i = 0; i < 4; ++i) o[i] = (f32x4){0.f, 0.f, 0.f, 0.f};
    float mst[4], lst[4];
#pragma unroll
    for (int r = 0; r < 4; ++r) { mst[r] = -INFINITY; lst[r] = 0.f; }

    const float* bias_base = bias + ((size_t)h * S_ + (q0 + quad * 4)) * S_;
    char* pw = smem + 32768 + wave * 2048;  // per-wave P buffer (bf16, swizzled)

    stage(0, 0);

    for (int it = 0; it < 32; ++it) {
        const int j0 = it * 64;
        const int bi = it & 1;
        __syncthreads();                 // buf[bi] ready (staged one iter ago)
        if (it < 31) stage(j0 + 64, bi ^ 1);  // overlaps with compute below

        const char* bK = smem + bi * 16384;
        const char* bV = bK + 8192;

        // bias (issued early; consumed after QK)
        float bb[16];
#pragma unroll
        for (int ng = 0; ng < 4; ++ng)
#pragma unroll
            for (int r = 0; r < 4; ++r)
                bb[ng * 4 + r] = bias_base[(size_t)r * S_ + j0 + ng * 16 + col];

        // ---- S = Q K^T ----
        f32x4 sc[4];
#pragma unroll
        for (int ng = 0; ng < 4; ++ng) {
            const char* rp = bK + (ng * 16 + col) * 128;
            short8 k0 = *(const short8*)(rp + sl0);
            short8 k1 = *(const short8*)(rp + sl1);
            f32x4 z = (f32x4){0.f, 0.f, 0.f, 0.f};
            z = MFMA16(aq0, k0, z);
            z = MFMA16(aq1, k1, z);
            sc[ng] = z;
        }
#pragma unroll
        for (int ng = 0; ng < 4; ++ng)
#pragma unroll
            for (int r = 0; r < 4; ++r) sc[ng][r] += bb[ng * 4 + r];

        // ---- online softmax ----
        float alpha[4], rs[4];
#pragma unroll
        for (int r = 0; r < 4; ++r) {
            float rm = fmaxf(fmaxf(sc[0][r], sc[1][r]), fmaxf(sc[2][r], sc[3][r]));
            rm = fmaxf(rm, __shfl_xor(rm, 1));
            rm = fmaxf(rm, __shfl_xor(rm, 2));
            rm = fmaxf(rm, __shfl_xor(rm, 4));
            rm = fmaxf(rm, __shfl_xor(rm, 8));
            float mn = fmaxf(mst[r], rm);
            alpha[r] = __expf(mst[r] - mn);
            mst[r] = mn;
            rs[r] = 0.f;
        }
#pragma unroll
        for (int ng = 0; ng < 4; ++ng)
#pragma unroll
            for (int r = 0; r < 4; ++r) {
                float p = __expf(sc[ng][r] - mst[r]);
                sc[ng][r] = p;
                rs[r] += p;
            }
#pragma unroll
        for (int r = 0; r < 4; ++r) {
            float s = rs[r];
            s += __shfl_xor(s, 1);
            s += __shfl_xor(s, 2);
            s += __shfl_xor(s, 4);
            s += __shfl_xor(s, 8);
            lst[r] = lst[r] * alpha[r] + s;
        }
#pragma unroll
        for (int ndg = 0; ndg < 4; ++ndg)
#pragma unroll
            for (int r = 0; r < 4; ++r) o[ndg][r] *= alpha[r];

        // ---- P (C-layout) -> bf16 swizzled LDS ----
#pragma unroll
        for (int ng = 0; ng < 4; ++ng) {
            const int cb = ng * 2 + (col >> 3);
#pragma unroll
            for (int r = 0; r < 4; ++r) {
                const int q = quad * 4 + r;
                *(u16*)(pw + q * 128 + ((cb ^ (q & 7)) * 16) + cx * 2) = f2bf(sc[ng][r]);
            }
        }
        // ---- A-layout P frags (row = col, chunk = kg*4+quad) ----
        short8 ap0 = *(const short8*)(pw + col * 128 + sl0);
        short8 ap1 = *(const short8*)(pw + col * 128 + sl1);

        // ---- O += P V ----
#pragma unroll
        for (int ndg = 0; ndg < 4; ++ndg) {
            const char* rp = bV + (ndg * 16 + col) * 128;
            short8 v0 = *(const short8*)(rp + sl0);
            short8 v1 = *(const short8*)(rp + sl1);
            o[ndg] = MFMA16(ap0, v0, o[ndg]);
            o[ndg] = MFMA16(ap1, v1, o[ndg]);
        }
    }

    // ---- epilogue ----
    float inv[4];
#pragma unroll
    for (int r = 0; r < 4; ++r) inv[r] = 1.f / lst[r];
#pragma unroll
    for (int ndg = 0; ndg < 4; ++ndg)
#pragma unroll
        for (int r = 0; r < 4; ++r)
            Ctx[(size_t)(b * S_ + q0 + quad * 4 + r) * D_ + h * 64 + ndg * 16 + col] =
                f2bf(o[ndg][r] * inv[r]);
}

// ---------------------------------------------------------------------------
// Launch
// ---------------------------------------------------------------------------
extern "C" void kernel_launch(void* const* d_in, const int* in_sizes, int n_in,
                              void* d_out, int out_size, void* d_ws, size_t ws_size,
                              hipStream_t stream) {
    const float* hs   = (const float*)d_in[0];
    const float* bias = (const float*)d_in[1];
    const float* wq   = (const float*)d_in[3];
    const float* wk   = (const float*)d_in[4];
    const float* wv   = (const float*)d_in[5];
    const float* wo   = (const float*)d_in[6];
    float* out = (float*)d_out;

    const size_t elems = (size_t)B_ * S_ * D_;
    char* ws = (char*)d_ws;
    u16* hs_bf = (u16*)ws;
    u16* qb    = (u16*)(ws + 8 * 1024 * 1024);
    u16* kb    = (u16*)(ws + 16 * 1024 * 1024);
    u16* vt    = (u16*)(ws + 24 * 1024 * 1024);
    u16* cb    = (u16*)(ws + 32 * 1024 * 1024);
    u16* wqt   = (u16*)(ws + 40 * 1024 * 1024);  // wqt/wkt/wvt contiguous
    u16* wkt   = (u16*)(ws + 42 * 1024 * 1024);
    u16* wvt   = (u16*)(ws + 44 * 1024 * 1024);
    u16* wot   = (u16*)(ws + 46 * 1024 * 1024);

    const int M = B_ * S_;

    cast_bf16<<<(int)(elems / (256 * 8)), 256, 0, stream>>>(hs, hs_bf);
    transpose_cast4<<<dim3(32, 32, 4), 256, 0, stream>>>(wq, wk, wv, wo,
                                                         wqt, wkt, wvt, wot);

    gemm_bf16<0><<<dim3(3 * D_ / 128, M / 128), 256, 0, stream>>>(
        hs_bf, wqt, (void*)qb, kb, vt, M, 3 * D_, D_);

    attn_mfma<<<B_ * H_ * (S_ / 64), 256, 0, stream>>>(qb, kb, vt, bias, cb);

    gemm_bf16<2><<<dim3(D_ / 128, M / 128), 256, 0, stream>>>(
        cb, wot, (void*)out, nullptr, nullptr, M, D_, D_);
}

// Round 4
// 522.350 us; speedup vs baseline: 5.0411x; 1.0120x over previous
//
#include <hip/hip_runtime.h>
#include <math.h>

#define B_  2
#define S_  2048
#define D_  1024
#define H_  16
#define DK_ 64

typedef float f32x4 __attribute__((ext_vector_type(4)));
typedef short short8 __attribute__((ext_vector_type(8)));
typedef unsigned short u16;

static __device__ __forceinline__ u16 f2bf(float x) {
    union { float f; unsigned u; } v; v.f = x;
    unsigned r = v.u + 0x7fffu + ((v.u >> 16) & 1u);
    return (u16)(r >> 16);
}

static __device__ __forceinline__ void gload_lds16(const void* g, void* l) {
    __builtin_amdgcn_global_load_lds((const __attribute__((address_space(1))) void*)g,
                                     (__attribute__((address_space(3))) void*)l,
                                     16, 0, 0);
}

#define MFMA16(a, b, c) __builtin_amdgcn_mfma_f32_16x16x32_bf16((a), (b), (c), 0, 0, 0)

// ---------------------------------------------------------------------------
// Fused prep: z=0..3 -> transpose+cast one 1024x1024 weight; z=4 -> cast hs.
// ---------------------------------------------------------------------------
__global__ __launch_bounds__(256) void prep(const float* __restrict__ hs,
                                            const float* __restrict__ w0,
                                            const float* __restrict__ w1,
                                            const float* __restrict__ w2,
                                            const float* __restrict__ w3,
                                            u16* __restrict__ hsb,
                                            u16* __restrict__ o0,
                                            u16* __restrict__ o1,
                                            u16* __restrict__ o2,
                                            u16* __restrict__ o3) {
    if (blockIdx.z == 4) {
        // cast: 1024 blocks x 256 threads x 16 elems
        size_t i = ((size_t)(blockIdx.y * 32 + blockIdx.x) * 256 + threadIdx.x) * 16;
#pragma unroll
        for (int c = 0; c < 2; ++c) {
            float4 a = *(const float4*)(hs + i + c * 8);
            float4 b = *(const float4*)(hs + i + c * 8 + 4);
            short8 o;
            o[0] = (short)f2bf(a.x); o[1] = (short)f2bf(a.y);
            o[2] = (short)f2bf(a.z); o[3] = (short)f2bf(a.w);
            o[4] = (short)f2bf(b.x); o[5] = (short)f2bf(b.y);
            o[6] = (short)f2bf(b.z); o[7] = (short)f2bf(b.w);
            *(short8*)(hsb + i + c * 8) = o;
        }
        return;
    }
    __shared__ float t[32][33];
    const float* W; u16* O;
    switch (blockIdx.z) {
        case 0: W = w0; O = o0; break;
        case 1: W = w1; O = o1; break;
        case 2: W = w2; O = o2; break;
        default: W = w3; O = o3; break;
    }
    const int K = 1024, N = 1024;
    int tx = threadIdx.x & 31, ty = threadIdx.x >> 5;
    int n0 = blockIdx.x * 32, k0 = blockIdx.y * 32;
#pragma unroll
    for (int r = ty; r < 32; r += 8)
        t[r][tx] = W[(size_t)(k0 + r) * N + n0 + tx];
    __syncthreads();
#pragma unroll
    for (int r = ty; r < 32; r += 8)
        O[(size_t)(n0 + r) * K + k0 + tx] = f2bf(t[tx][r]);
}

// ---------------------------------------------------------------------------
// bf16 MFMA GEMM, 128x128 tile, BK=32, DOUBLE-BUFFERED LDS (one barrier/iter;
// stage(it+1) issued right after the barrier, drained a full compute phase
// later — same structure that halved the attention kernel).
// __launch_bounds__(256,2): pin >=2 blocks/CU (VGPR cap 256; est ~130 used).
// MODE 0: fused QKV epilogue -> Qb, Kb, Vt[b][h][d][s].  MODE 2: fp32 out.
// ---------------------------------------------------------------------------
template <int MODE>
__global__ __launch_bounds__(256, 2) void gemm_bf16(const u16* __restrict__ A,
                                                    const u16* __restrict__ Bt,
                                                    void* __restrict__ C0,
                                                    u16* __restrict__ Kb,
                                                    u16* __restrict__ Vt,
                                                    int M, int N, int K) {
    __shared__ alignas(16) u16 As[2][128 * 32];
    __shared__ alignas(16) u16 Bs[2][128 * 32];

    const int tid  = threadIdx.x;
    const int wave = tid >> 6;
    const int lane = tid & 63;
    const int col  = lane & 15;
    const int quad = lane >> 4;
    const int bm   = blockIdx.y * 128;
    const int bn   = blockIdx.x * 128;
    const int wm   = (wave >> 1) * 64;
    const int wn   = (wave & 1) * 64;

    f32x4 acc[4][4];
#pragma unroll
    for (int i = 0; i < 4; ++i)
#pragma unroll
        for (int j = 0; j < 4; ++j) acc[i][j] = (f32x4){0.f, 0.f, 0.f, 0.f};

    const int srow = wave * 32 + (lane >> 2);
    const int ksel = (lane & 3) * 8;
    const u16* gA = A  + (size_t)(bm + srow) * K + ksel;
    const u16* gB = Bt + (size_t)(bn + srow) * K + ksel;
    const size_t rowJump = (size_t)16 * K;
    const int ldsOff = wave * 2048;

    auto stage = [&](int k0, int bi) {
        char* a = (char*)As[bi] + ldsOff;
        char* b = (char*)Bs[bi] + ldsOff;
        gload_lds16(gA + k0, a);
        gload_lds16(gA + k0 + rowJump, a + 1024);
        gload_lds16(gB + k0, b);
        gload_lds16(gB + k0 + rowJump, b + 1024);
    };

    stage(0, 0);
    const int NIT = K >> 5;
    for (int it = 0; it < NIT; ++it) {
        const int bi = it & 1;
        __syncthreads();                     // buf[bi] ready (staged one iter ago)
        if (it + 1 < NIT) stage((it + 1) * 32, bi ^ 1);

        const u16* as = As[bi];
        const u16* bs = Bs[bi];
        short8 af[4], bfr[4];
#pragma unroll
        for (int mi = 0; mi < 4; ++mi)
            af[mi] = *(const short8*)&as[(wm + mi * 16 + col) * 32 + quad * 8];
#pragma unroll
        for (int ni = 0; ni < 4; ++ni)
            bfr[ni] = *(const short8*)&bs[(wn + ni * 16 + col) * 32 + quad * 8];
#pragma unroll
        for (int mi = 0; mi < 4; ++mi)
#pragma unroll
            for (int ni = 0; ni < 4; ++ni)
                acc[mi][ni] = MFMA16(af[mi], bfr[ni], acc[mi][ni]);
    }

#pragma unroll
    for (int mi = 0; mi < 4; ++mi)
#pragma unroll
        for (int ni = 0; ni < 4; ++ni) {
            const int rowb = bm + wm + mi * 16 + quad * 4;
            const int coln = bn + wn + ni * 16 + col;
            f32x4 v = acc[mi][ni];
            if (MODE == 2) {
                float* O = (float*)C0;
#pragma unroll
                for (int r = 0; r < 4; ++r)
                    O[(size_t)(rowb + r) * N + coln] = v[r];
            } else {
                if (coln < D_) {
                    u16* Qb = (u16*)C0;
#pragma unroll
                    for (int r = 0; r < 4; ++r)
                        Qb[(size_t)(rowb + r) * D_ + coln] = f2bf(v[r]);
                } else if (coln < 2 * D_) {
#pragma unroll
                    for (int r = 0; r < 4; ++r)
                        Kb[(size_t)(rowb + r) * D_ + (coln - D_)] = f2bf(v[r]);
                } else {
                    const int nn = coln - 2 * D_;
                    const int hh = nn >> 6, d = nn & 63;
                    const int bb = rowb >> 11, sb = rowb & 2047;
                    ushort4 pk;
                    pk.x = f2bf(v[0]); pk.y = f2bf(v[1]);
                    pk.z = f2bf(v[2]); pk.w = f2bf(v[3]);
                    *(ushort4*)&Vt[(((size_t)bb * H_ + hh) * DK_ + d) * S_ + sb] = pk;
                }
            }
        }
}

// ---------------------------------------------------------------------------
// MFMA flash attention (unchanged from round 3 — validated).
// ---------------------------------------------------------------------------
__global__ __launch_bounds__(256, 4) void attn_mfma(const u16* __restrict__ Qb,
                                                    const u16* __restrict__ Kb,
                                                    const u16* __restrict__ Vt,
                                                    const float* __restrict__ bias,
                                                    u16* __restrict__ Ctx) {
    __shared__ alignas(16) char smem[40960];  // K0 V0 K1 V1 (8KB each) + Ps 8KB

    const int tid  = threadIdx.x;
    const int wave = tid >> 6;
    const int lane = tid & 63;
    const int col  = lane & 15;
    const int quad = lane >> 4;
    const int cx   = col & 7;
    const int sl0  = (quad ^ cx) * 16;
    const int sl1  = ((4 + quad) ^ cx) * 16;

    const int gid = blockIdx.x;
    const int qt  = gid & 31;
    const int h   = (gid >> 5) & 15;
    const int b   = gid >> 9;
    const int q0  = qt * 64 + wave * 16;

    short8 aq0, aq1;
    {
        const u16* qp = Qb + (size_t)(b * S_ + q0 + col) * D_ + h * 64 + quad * 8;
        aq0 = *(const short8*)qp;
        aq1 = *(const short8*)(qp + 32);
    }

    const int c0 = tid, c1 = tid + 256;
    const int r0 = c0 >> 3, g0 = (c0 & 7) ^ (r0 & 7);
    const int r1 = c1 >> 3, g1 = (c1 & 7) ^ (r1 & 7);
    const u16* kT = Kb + (size_t)b * S_ * D_ + h * 64;
    const u16* vT = Vt + ((size_t)b * H_ + h) * (size_t)64 * S_;
    const size_t kOff0 = (size_t)r0 * D_ + g0 * 8;
    const size_t kOff1 = (size_t)r1 * D_ + g1 * 8;
    const size_t vOff0 = (size_t)r0 * S_ + g0 * 8;
    const size_t vOff1 = (size_t)r1 * S_ + g1 * 8;

    auto stage = [&](int j0s, int bis) {
        char* base = smem + bis * 16384;
        gload_lds16(kT + (size_t)j0s * D_ + kOff0, base + wave * 1024);
        gload_lds16(kT + (size_t)j0s * D_ + kOff1, base + 4096 + wave * 1024);
        gload_lds16(vT + j0s + vOff0, base + 8192 + wave * 1024);
        gload_lds16(vT + j0s + vOff1, base + 12288 + wave * 1024);
    };

    f32x4 o[4];
#pragma unroll
    for (int i = 0; i < 4; ++i) o[i] = (f32x4){0.f, 0.f, 0.f, 0.f};
    float mst[4], lst[4];
#pragma unroll
    for (int r = 0; r < 4; ++r) { mst[r] = -INFINITY; lst[r] = 0.f; }

    const float* bias_base = bias + ((size_t)h * S_ + (q0 + quad * 4)) * S_;
    char* pw = smem + 32768 + wave * 2048;

    stage(0, 0);

    for (int it = 0; it < 32; ++it) {
        const int j0 = it * 64;
        const int bi = it & 1;
        __syncthreads();
        if (it < 31) stage(j0 + 64, bi ^ 1);

        const char* bK = smem + bi * 16384;
        const char* bV = bK + 8192;

        float bb[16];
#pragma unroll
        for (int ng = 0; ng < 4; ++ng)
#pragma unroll
            for (int r = 0; r < 4; ++r)
                bb[ng * 4 + r] = bias_base[(size_t)r * S_ + j0 + ng * 16 + col];

        f32x4 sc[4];
#pragma unroll
        for (int ng = 0; ng < 4; ++ng) {
            const char* rp = bK + (ng * 16 + col) * 128;
            short8 k0 = *(const short8*)(rp + sl0);
            short8 k1 = *(const short8*)(rp + sl1);
            f32x4 z = (f32x4){0.f, 0.f, 0.f, 0.f};
            z = MFMA16(aq0, k0, z);
            z = MFMA16(aq1, k1, z);
            sc[ng] = z;
        }
#pragma unroll
        for (int ng = 0; ng < 4; ++ng)
#pragma unroll
            for (int r = 0; r < 4; ++r) sc[ng][r] += bb[ng * 4 + r];

        float alpha[4], rs[4];
#pragma unroll
        for (int r = 0; r < 4; ++r) {
            float rm = fmaxf(fmaxf(sc[0][r], sc[1][r]), fmaxf(sc[2][r], sc[3][r]));
            rm = fmaxf(rm, __shfl_xor(rm, 1));
            rm = fmaxf(rm, __shfl_xor(rm, 2));
            rm = fmaxf(rm, __shfl_xor(rm, 4));
            rm = fmaxf(rm, __shfl_xor(rm, 8));
            float mn = fmaxf(mst[r], rm);
            alpha[r] = __expf(mst[r] - mn);
            mst[r] = mn;
            rs[r] = 0.f;
        }
#pragma unroll
        for (int ng = 0; ng < 4; ++ng)
#pragma unroll
            for (int r = 0; r < 4; ++r) {
                float p = __expf(sc[ng][r] - mst[r]);
                sc[ng][r] = p;
                rs[r] += p;
            }
#pragma unroll
        for (int r = 0; r < 4; ++r) {
            float s = rs[r];
            s += __shfl_xor(s, 1);
            s += __shfl_xor(s, 2);
            s += __shfl_xor(s, 4);
            s += __shfl_xor(s, 8);
            lst[r] = lst[r] * alpha[r] + s;
        }
#pragma unroll
        for (int ndg = 0; ndg < 4; ++ndg)
#pragma unroll
            for (int r = 0; r < 4; ++r) o[ndg][r] *= alpha[r];

#pragma unroll
        for (int ng = 0; ng < 4; ++ng) {
            const int cb = ng * 2 + (col >> 3);
#pragma unroll
            for (int r = 0; r < 4; ++r) {
                const int q = quad * 4 + r;
                *(u16*)(pw + q * 128 + ((cb ^ (q & 7)) * 16) + cx * 2) = f2bf(sc[ng][r]);
            }
        }
        short8 ap0 = *(const short8*)(pw + col * 128 + sl0);
        short8 ap1 = *(const short8*)(pw + col * 128 + sl1);

#pragma unroll
        for (int ndg = 0; ndg < 4; ++ndg) {
            const char* rp = bV + (ndg * 16 + col) * 128;
            short8 v0 = *(const short8*)(rp + sl0);
            short8 v1 = *(const short8*)(rp + sl1);
            o[ndg] = MFMA16(ap0, v0, o[ndg]);
            o[ndg] = MFMA16(ap1, v1, o[ndg]);
        }
    }

    float inv[4];
#pragma unroll
    for (int r = 0; r < 4; ++r) inv[r] = 1.f / lst[r];
#pragma unroll
    for (int ndg = 0; ndg < 4; ++ndg)
#pragma unroll
        for (int r = 0; r < 4; ++r)
            Ctx[(size_t)(b * S_ + q0 + quad * 4 + r) * D_ + h * 64 + ndg * 16 + col] =
                f2bf(o[ndg][r] * inv[r]);
}

// ---------------------------------------------------------------------------
// Launch
// ---------------------------------------------------------------------------
extern "C" void kernel_launch(void* const* d_in, const int* in_sizes, int n_in,
                              void* d_out, int out_size, void* d_ws, size_t ws_size,
                              hipStream_t stream) {
    const float* hs   = (const float*)d_in[0];
    const float* bias = (const float*)d_in[1];
    const float* wq   = (const float*)d_in[3];
    const float* wk   = (const float*)d_in[4];
    const float* wv   = (const float*)d_in[5];
    const float* wo   = (const float*)d_in[6];
    float* out = (float*)d_out;

    char* ws = (char*)d_ws;
    u16* hs_bf = (u16*)ws;
    u16* qb    = (u16*)(ws + 8 * 1024 * 1024);
    u16* kb    = (u16*)(ws + 16 * 1024 * 1024);
    u16* vt    = (u16*)(ws + 24 * 1024 * 1024);
    u16* cb    = (u16*)(ws + 32 * 1024 * 1024);
    u16* wqt   = (u16*)(ws + 40 * 1024 * 1024);  // wqt/wkt/wvt contiguous
    u16* wkt   = (u16*)(ws + 42 * 1024 * 1024);
    u16* wvt   = (u16*)(ws + 44 * 1024 * 1024);
    u16* wot   = (u16*)(ws + 46 * 1024 * 1024);

    const int M = B_ * S_;

    prep<<<dim3(32, 32, 5), 256, 0, stream>>>(hs, wq, wk, wv, wo,
                                              hs_bf, wqt, wkt, wvt, wot);

    gemm_bf16<0><<<dim3(3 * D_ / 128, M / 128), 256, 0, stream>>>(
        hs_bf, wqt, (void*)qb, kb, vt, M, 3 * D_, D_);

    attn_mfma<<<B_ * H_ * (S_ / 64), 256, 0, stream>>>(qb, kb, vt, bias, cb);

    gemm_bf16<2><<<dim3(D_ / 128, M / 128), 256, 0, stream>>>(
        cb, wot, (void*)out, nullptr, nullptr, M, D_, D_);
}